// Round 19
// baseline (209.248 us; speedup 1.0000x reference)
//
#include <hip/hip_runtime.h>
#include <hip/hip_fp16.h>
#include <math.h>

#define B 4
#define C 21
#define NP 11
#define H 256
#define W 256
#define HW (H*W)
#define NPIX (B*HW)
#define NB2 (B*NP*HW)

// update: 16x16 tile, 1 px/thread, sparse tap lists. grid B*256=1024 -> 16 waves/CU
#define R 6
#define HR 28                // halo size
#define HXP 29               // padded LDS row stride
#define NSU (HR*HR)          // 784 records
#define NSLOT (27*HXP + 28)  // 811 slots

#define CAP 48               // max stored in-image taps per px (multiple of 4)

#define C2F ((float)(1.4426950408889634 / 338.0))
#define L2E 1.4426950408889634f

// gauss geometry
#define GOY 64
#define GTR (GOY + 18)
#define GTS 17

union U4 { uint4 u; __half2 h[4]; };
union Hu { unsigned int u32; __half2 h; };

__device__ __forceinline__ float fexp2(float x) {
    float r;
    asm("v_exp_f32 %0, %1" : "=v"(r) : "v"(x));
    return r;
}

typedef __fp16 f16x2 __attribute__((ext_vector_type(2)));
__device__ __forceinline__ __half2 h2bcast(float w) {
    f16x2 t = __builtin_amdgcn_cvt_pkrtz(w, w);   // exact: integer 0..255
    return *(__half2*)&t;
}
#define SEL01 0x05000400u
#define SEL23 0x07000600u
__device__ __forceinline__ __half2 pe5(unsigned int qw, unsigned int sel) {
    Hu h; h.u32 = __builtin_amdgcn_perm(qw, 0u, sel);
    return h.h;
}
__device__ __forceinline__ unsigned int pk_e5m2(float a, float b) {
    f16x2 t = __builtin_amdgcn_cvt_pkrtz(a, b);
    unsigned int h = *(unsigned int*)&t;
    unsigned int lo = ((h & 0xFFFFu) + 0x80u) >> 8;
    unsigned int hi = (((h >> 16) & 0xFFFFu) + 0x80u) >> 8;
    return lo | (hi << 8);
}

// ---------------------------------------------------------------------------
// Init: U packed f16; Q0 -> pair-f16 planar (gauss) + e5m2 px-records (update).
__global__ __launch_bounds__(256) void k_init(const float* __restrict__ logits,
                                              unsigned int* __restrict__ Upk,
                                              unsigned int* __restrict__ Qp,
                                              uint4* __restrict__ Q8a,
                                              uint2* __restrict__ Q8b,
                                              float* __restrict__ kt) {
    int p = blockIdx.x * 256 + threadIdx.x;
    if (p == 0) {
        float e[19]; float s0 = 0.f;
        for (int i = 0; i < 19; ++i) {
            double d = (double)(i - 9);
            e[i] = (float)exp(-(d*d) / 18.0);
            s0 += e[i];
        }
        for (int i = 0; i < 19; ++i) kt[i] = e[i] / s0;
        float k9 = e[9] / s0;
        kt[19] = k9 * k9;
        kt[20] = 1.f - k9 * k9;
    }
    int b = p >> 16, g = p & (HW - 1);
    const float* lp = logits + (size_t)b * C * HW + g;

    float v[C];
    float m = -1e30f;
#pragma unroll
    for (int c = 0; c < C; ++c) { v[c] = lp[c*HW]; m = fmaxf(m, v[c]); }
    float s = 0.f;
#pragma unroll
    for (int c = 0; c < C; ++c) { v[c] = __expf(v[c] - m); s += v[c]; }
    float inv = 1.f / s;

    float u[C];
    float m2 = -1e30f;
#pragma unroll
    for (int c = 0; c < C; ++c) {
        float sm = fminf(fmaxf(v[c] * inv, 1e-5f), 1.f);
        float uu = -__logf(sm);
        u[c] = uu;
        m2 = fmaxf(m2, -uu);
    }
    float s2 = 0.f;
    float q[C + 1];
#pragma unroll
    for (int c = 0; c < C; ++c) { q[c] = __expf(-u[c] - m2); s2 += q[c]; }
    float inv2 = 1.f / s2;
#pragma unroll
    for (int c = 0; c < C; ++c) q[c] *= inv2;
    q[C] = 0.f;

    unsigned int* Ub = Upk + (size_t)b * NP * HW + g;
    unsigned int* Qb = Qp + (size_t)b * NP * HW + g;
#pragma unroll
    for (int k = 0; k < NP; ++k) {
        Hu xu; xu.h = __floats2half2_rn(u[2*k], (2*k+1 < C) ? u[2*k+1] : 0.f);
        Ub[k*HW] = xu.u32;
        Hu xq; xq.h = __floats2half2_rn(q[2*k], q[2*k+1]);
        Qb[k*HW] = xq.u32;
    }
    unsigned int w8[6];
#pragma unroll
    for (int j = 0; j < 5; ++j)
        w8[j] = pk_e5m2(q[4*j], q[4*j+1]) | (pk_e5m2(q[4*j+2], q[4*j+3]) << 16);
    w8[5] = pk_e5m2(q[20], 0.f);
    Q8a[p] = make_uint4(w8[0], w8[1], w8[2], w8[3]);
    Q8b[p] = make_uint2(w8[4], w8[5]);
}

// ---------------------------------------------------------------------------
// Sparse weight lists: per px, store nonzero IN-IMAGE taps as u32 = w | recoff<<8
// (recoff = d*HXP + j); out-of-image taps fold into WPAD (wsum only). Remaining
// slots up to CAP are ZERO-FILLED so k_update can run unpredicated groups of 4.
__global__ __launch_bounds__(256) void k_wgt(const float* __restrict__ img,
                                             unsigned int* __restrict__ ENT,
                                             unsigned int* __restrict__ CNT,
                                             unsigned int* __restrict__ WPAD) {
    __shared__ float4 IRGB[NSU];

    int blk = blockIdx.x;
    int b = blk >> 8;
    int tile = blk & 255;
    int ty0 = (tile >> 4) * 16;
    int tx0 = (tile & 15) * 16;
    int tid = threadIdx.x;

    const float* Ib = img + (size_t)b * 3 * HW;
    for (int s = tid; s < NSU; s += 256) {
        int ly = s / HR, lx = s - ly * HR;
        int gy = ty0 + ly - R, gx = tx0 + lx - R;
        bool in = ((unsigned)gy < (unsigned)H) && ((unsigned)gx < (unsigned)W);
        int g = gy * W + gx;
        float r = 0.f, gg = 0.f, bb = 0.f;
        if (in) {
            r  = floorf(fminf(fmaxf(Ib[g]        * 255.f, 0.f), 255.f));
            gg = floorf(fminf(fmaxf(Ib[HW + g]   * 255.f, 0.f), 255.f));
            bb = floorf(fminf(fmaxf(Ib[2*HW + g] * 255.f, 0.f), 255.f));
        }
        IRGB[s] = make_float4(r, gg, bb, 0.f);
    }
    __syncthreads();

    int x = tid & 15, r = tid >> 4;
    float4 c0 = IRGB[(r + 6) * HR + x + 6];

    float cc[13];
#pragma unroll
    for (int j = 0; j < 13; ++j) cc[j] = -(float)((j-6)*(j-6)) * C2F;

    unsigned int* eb = ENT + (size_t)blk * (CAP * 256) + tid;
    unsigned int cnt = 0u, wpad = 0u;

    for (int d = 0; d < 13; ++d) {
        int gy = ty0 + r + d - 6;
        int rowb = (r + d) * HR + x;
        float a0 = cc[d];
#pragma unroll
        for (int j = 0; j < 13; ++j) {
            if (d == 6 && j == 6) continue;              // exact center exclusion
            float4 n = IRGB[rowb + j];
            float dr = c0.x - n.x, dg = c0.y - n.y, db = c0.z - n.z;
            float ss = fmaf(dr, dr, fmaf(dg, dg, db * db));
            float w = fexp2(fmaf(ss, -C2F, a0 + cc[j]));
            unsigned int u0 = (unsigned int)fmaf(w, 255.f, 0.5f);
            if (u0 == 0u) continue;
            int gx = tx0 + x + j - 6;
            bool in = ((unsigned)gy < (unsigned)H) && ((unsigned)gx < (unsigned)W);
            if (in) {
                if (cnt < CAP) { eb[cnt * 256] = u0 | ((unsigned int)(d * HXP + j) << 8); ++cnt; }
            } else {
                wpad += u0;   // zero-padded Q: contributes to wsum only
            }
        }
    }
    // zero-fill remaining slots (w=0, recoff=0 -> reads own record, adds exact 0)
    for (unsigned int s = cnt; s < CAP; ++s) eb[s * 256] = 0u;
    CNT[blk * 256 + tid]  = cnt;
    WPAD[blk * 256 + tid] = wpad;
}

// ---------------------------------------------------------------------------
// Fused separable Gaussian + message (pair-f16 planar, unchanged).
__global__ __launch_bounds__(256) void k_gauss(const unsigned int* __restrict__ Q,
                                               unsigned int* __restrict__ MG,
                                               const float* __restrict__ kt) {
    __shared__ uint4 T[GTR * GTS];
    __shared__ float kf[21];

    int tid = threadIdx.x;
    if (tid < 21) kf[tid] = kt[tid];
    __syncthreads();

    __half2 kh[19];
#pragma unroll
    for (int j = 0; j < 19; ++j) kh[j] = __float2half2_rn(kf[j]);

    int blk = blockIdx.x;
    int pl  = blk >> 4;
    int sub = blk & 15;
    int y0 = (sub >> 2) * GOY;
    int x0 = (sub & 3) * 64;
    const unsigned int* base = Q + (size_t)pl * HW;

    for (int s = tid; s < GTR * 16; s += 256) {
        int row = s >> 4;
        int q   = s & 15;
        int yy = y0 + row - 9;
        U4 o;
        o.u = make_uint4(0u, 0u, 0u, 0u);
        if ((unsigned)yy < (unsigned)H) {
            int xb = x0 + q * 4;
            const unsigned int* rp = base + yy * W;
            U4 ch[7];
#pragma unroll
            for (int c2 = 0; c2 < 7; ++c2) {
                int xq = xb - 12 + c2 * 4;
                if ((unsigned)xq < (unsigned)W) ch[c2].u = *(const uint4*)(rp + xq);
                else ch[c2].u = make_uint4(0u,0u,0u,0u);
            }
            const __half2* v = (const __half2*)ch;
#pragma unroll
            for (int i = 0; i < 4; ++i) {
                __half2 acc = __float2half2_rn(0.f);
#pragma unroll
                for (int j = 0; j < 19; ++j) acc = __hfma2(kh[j], v[i + 3 + j], acc);
                o.h[i] = acc;
            }
        }
        T[row * GTS + q] = o.u;
    }
    __syncthreads();

    __half2 nw0  = __float2half2_rn(-kf[19]);
    __half2 inv1 = __float2half2_rn(1.f / kf[20]);
    int q  = tid & 15;
    int rg = tid >> 4;
    int r0 = rg * 4;

    __half2 acc[4][4];
#pragma unroll
    for (int i = 0; i < 4; ++i)
#pragma unroll
        for (int qd = 0; qd < 4; ++qd) acc[i][qd] = __float2half2_rn(0.f);

#pragma unroll
    for (int j = 0; j < 22; ++j) {
        U4 f; f.u = T[(r0 + j) * GTS + q];
#pragma unroll
        for (int i = 0; i < 4; ++i) {
            int tap = j - i;
            if (tap >= 0 && tap <= 18) {
#pragma unroll
                for (int qd = 0; qd < 4; ++qd)
                    acc[i][qd] = __hfma2(kh[tap], f.h[qd], acc[i][qd]);
            }
        }
    }

#pragma unroll
    for (int i = 0; i < 4; ++i) {
        size_t e = (size_t)pl * HW + (y0 + r0 + i) * W + x0 + q * 4;
        U4 qq; qq.u = *(const uint4*)(Q + e);
        U4 o;
#pragma unroll
        for (int qd = 0; qd < 4; ++qd)
            o.h[qd] = __hmul2(__hfma2(nw0, qq.h[qd], acc[i][qd]), inv1);
        *(uint4*)(MG + e) = o.u;
    }
}

// ---------------------------------------------------------------------------
// Sparse bilateral + update: 1 px/thread, group-of-4 unrolled tap loop
// (zero-padded entries need no predication; 8 LDS gathers in flight per group).
__global__ __launch_bounds__(256, 4) void k_update(const uint4* __restrict__ Q8a,
                                                   const uint2* __restrict__ Q8b,
                                                   const unsigned int* __restrict__ Upk,
                                                   const unsigned int* __restrict__ MG,
                                                   const unsigned int* __restrict__ ENT,
                                                   const unsigned int* __restrict__ CNT,
                                                   const unsigned int* __restrict__ WPAD,
                                                   unsigned int* __restrict__ Qn,
                                                   uint4* __restrict__ Q8na,
                                                   uint2* __restrict__ Q8nb,
                                                   const int* __restrict__ labels,
                                                   float* __restrict__ part) {
    __shared__ uint4 LA[NSLOT];   // ch 0..15 e5m2 (13.0 KB)
    __shared__ uint2 L5[NSLOT];   // ch 16..20 (6.5 KB)
    __shared__ float red[4];

    int blk = blockIdx.x;
    int b = blk >> 8;
    int tile = blk & 255;
    int ty0 = (tile >> 4) * 16;
    int tx0 = (tile & 15) * 16;
    int tid = threadIdx.x;

    const uint4* Qa = Q8a + (size_t)b * HW;
    const uint2* Qb = Q8b + (size_t)b * HW;

#pragma unroll
    for (int i = 0; i < 4; ++i) {
        int s = tid + i * 256;
        if (s < NSU) {
            int ly = s / HR;
            int lx = s - ly * HR;
            int gy = ty0 + ly - R;
            int gx = tx0 + lx - R;
            bool in = ((unsigned)gy < (unsigned)H) && ((unsigned)gx < (unsigned)W);
            int g = gy * W + gx;
            uint4 a = in ? Qa[g] : make_uint4(0u, 0u, 0u, 0u);
            uint2 c = in ? Qb[g] : make_uint2(0u, 0u);
            int p = ly * HXP + lx;
            LA[p] = a;
            L5[p] = c;
        }
    }
    __syncthreads();

    int x = tid & 15;
    int r = tid >> 4;
    int g0 = (ty0 + r) * W + (tx0 + x);
    int pbase = r * HXP + x;

    // epilogue prefetch
    const unsigned int* Ub = Upk + (size_t)b * NP * HW + g0;
    const unsigned int* Mb = MG + (size_t)b * NP * HW + g0;
    unsigned int pfU[NP], pfM[NP];
#pragma unroll
    for (int k = 0; k < NP; ++k) { pfU[k] = Ub[k*HW]; pfM[k] = Mb[k*HW]; }

    int cnt = (int)CNT[blk * 256 + tid];
    unsigned int wsi = WPAD[blk * 256 + tid];
    const unsigned int* eb = ENT + (size_t)blk * (CAP * 256) + tid;

    __half2 m0[NP];
#pragma unroll
    for (int k = 0; k < NP; ++k) m0[k] = __float2half2_rn(0.f);

    for (int s0 = 0; __any(s0 < cnt); s0 += 4) {
        unsigned int e0 = eb[(s0 + 0) * 256];
        unsigned int e1 = eb[(s0 + 1) * 256];
        unsigned int e2 = eb[(s0 + 2) * 256];
        unsigned int e3 = eb[(s0 + 3) * 256];
        int p0 = pbase + (int)(e0 >> 8);
        int p1 = pbase + (int)(e1 >> 8);
        int p2 = pbase + (int)(e2 >> 8);
        int p3 = pbase + (int)(e3 >> 8);
        U4 A0, A1, A2, A3;
        A0.u = LA[p0]; A1.u = LA[p1]; A2.u = LA[p2]; A3.u = LA[p3];
        uint2 c0 = L5[p0], c1 = L5[p1], c2 = L5[p2], c3 = L5[p3];
        __half2 w0 = h2bcast((float)(e0 & 0xffu));
        __half2 w1 = h2bcast((float)(e1 & 0xffu));
        __half2 w2 = h2bcast((float)(e2 & 0xffu));
        __half2 w3 = h2bcast((float)(e3 & 0xffu));
        wsi += (e0 & 0xffu) + (e1 & 0xffu) + (e2 & 0xffu) + (e3 & 0xffu);

        m0[0] = __hfma2(w0, pe5(A0.u.x, SEL01), m0[0]);
        m0[1] = __hfma2(w0, pe5(A0.u.x, SEL23), m0[1]);
        m0[2] = __hfma2(w0, pe5(A0.u.y, SEL01), m0[2]);
        m0[3] = __hfma2(w0, pe5(A0.u.y, SEL23), m0[3]);
        m0[4] = __hfma2(w0, pe5(A0.u.z, SEL01), m0[4]);
        m0[5] = __hfma2(w0, pe5(A0.u.z, SEL23), m0[5]);
        m0[6] = __hfma2(w0, pe5(A0.u.w, SEL01), m0[6]);
        m0[7] = __hfma2(w0, pe5(A0.u.w, SEL23), m0[7]);
        m0[8] = __hfma2(w0, pe5(c0.x, SEL01), m0[8]);
        m0[9] = __hfma2(w0, pe5(c0.x, SEL23), m0[9]);
        m0[10] = __hfma2(w0, pe5(c0.y, SEL01), m0[10]);

        m0[0] = __hfma2(w1, pe5(A1.u.x, SEL01), m0[0]);
        m0[1] = __hfma2(w1, pe5(A1.u.x, SEL23), m0[1]);
        m0[2] = __hfma2(w1, pe5(A1.u.y, SEL01), m0[2]);
        m0[3] = __hfma2(w1, pe5(A1.u.y, SEL23), m0[3]);
        m0[4] = __hfma2(w1, pe5(A1.u.z, SEL01), m0[4]);
        m0[5] = __hfma2(w1, pe5(A1.u.z, SEL23), m0[5]);
        m0[6] = __hfma2(w1, pe5(A1.u.w, SEL01), m0[6]);
        m0[7] = __hfma2(w1, pe5(A1.u.w, SEL23), m0[7]);
        m0[8] = __hfma2(w1, pe5(c1.x, SEL01), m0[8]);
        m0[9] = __hfma2(w1, pe5(c1.x, SEL23), m0[9]);
        m0[10] = __hfma2(w1, pe5(c1.y, SEL01), m0[10]);

        m0[0] = __hfma2(w2, pe5(A2.u.x, SEL01), m0[0]);
        m0[1] = __hfma2(w2, pe5(A2.u.x, SEL23), m0[1]);
        m0[2] = __hfma2(w2, pe5(A2.u.y, SEL01), m0[2]);
        m0[3] = __hfma2(w2, pe5(A2.u.y, SEL23), m0[3]);
        m0[4] = __hfma2(w2, pe5(A2.u.z, SEL01), m0[4]);
        m0[5] = __hfma2(w2, pe5(A2.u.z, SEL23), m0[5]);
        m0[6] = __hfma2(w2, pe5(A2.u.w, SEL01), m0[6]);
        m0[7] = __hfma2(w2, pe5(A2.u.w, SEL23), m0[7]);
        m0[8] = __hfma2(w2, pe5(c2.x, SEL01), m0[8]);
        m0[9] = __hfma2(w2, pe5(c2.x, SEL23), m0[9]);
        m0[10] = __hfma2(w2, pe5(c2.y, SEL01), m0[10]);

        m0[0] = __hfma2(w3, pe5(A3.u.x, SEL01), m0[0]);
        m0[1] = __hfma2(w3, pe5(A3.u.x, SEL23), m0[1]);
        m0[2] = __hfma2(w3, pe5(A3.u.y, SEL01), m0[2]);
        m0[3] = __hfma2(w3, pe5(A3.u.y, SEL23), m0[3]);
        m0[4] = __hfma2(w3, pe5(A3.u.z, SEL01), m0[4]);
        m0[5] = __hfma2(w3, pe5(A3.u.z, SEL23), m0[5]);
        m0[6] = __hfma2(w3, pe5(A3.u.w, SEL01), m0[6]);
        m0[7] = __hfma2(w3, pe5(A3.u.w, SEL23), m0[7]);
        m0[8] = __hfma2(w3, pe5(c3.x, SEL01), m0[8]);
        m0[9] = __hfma2(w3, pe5(c3.x, SEL23), m0[9]);
        m0[10] = __hfma2(w3, pe5(c3.y, SEL01), m0[10]);
    }

    float inv = 1.f / ((float)wsi + 2.55e-6f);

    // Epilogue (log2-domain softmax); write f16 Q + e5m2 Q, or NLL on last iter.
    float sv[C + 1];
    float mm = -1e30f;
#pragma unroll
    for (int k = 0; k < NP; ++k) {
        float2 mf = __half22float2(m0[k]);
        Hu mgu; mgu.u32 = pfM[k];
        float2 mgf = __half22float2(mgu.h);
        Hu uu; uu.u32 = pfU[k];
        float2 uf = __half22float2(uu.h);
        int c0 = 2 * k;
        float v0 = fmaf(-L2E, uf.x, fmaf(3.f*L2E, mgf.x, (10.f*L2E) * (mf.x * inv)));
        sv[c0] = v0; mm = fmaxf(mm, v0);
        if (c0 + 1 < C) {
            float v1 = fmaf(-L2E, uf.y, fmaf(3.f*L2E, mgf.y, (10.f*L2E) * (mf.y * inv)));
            sv[c0+1] = v1; mm = fmaxf(mm, v1);
        }
    }
    float s = 0.f;
#pragma unroll
    for (int c = 0; c < C; ++c) { sv[c] = fexp2(sv[c] - mm); s += sv[c]; }

    if (labels) {
        int lab = labels[(size_t)b * HW + g0];
        float qsum = 0.f, ql = 1e-8f;
#pragma unroll
        for (int c = 0; c < C; ++c) {
            float qc = sv[c] / s + 1e-8f;
            qsum += qc;
            if (c == lab) ql = qc;
        }
        float nll = __logf(qsum) - __logf(ql);
#pragma unroll
        for (int off = 32; off > 0; off >>= 1) nll += __shfl_down(nll, off);
        int lane = tid & 63, wv = tid >> 6;
        if (lane == 0) red[wv] = nll;
        __syncthreads();
        if (tid == 0) part[blk] = red[0] + red[1] + red[2] + red[3];
    } else {
        float is = 1.f / s;
#pragma unroll
        for (int c = 0; c < C; ++c) sv[c] *= is;
        sv[C] = 0.f;
        unsigned int* Qo = Qn + (size_t)b * NP * HW + g0;
#pragma unroll
        for (int k = 0; k < NP; ++k) {
            Hu xh; xh.h = __floats2half2_rn(sv[2*k], sv[2*k+1]);
            Qo[k*HW] = xh.u32;
        }
        unsigned int w8[6];
#pragma unroll
        for (int j = 0; j < 5; ++j)
            w8[j] = pk_e5m2(sv[4*j], sv[4*j+1]) | (pk_e5m2(sv[4*j+2], sv[4*j+3]) << 16);
        w8[5] = pk_e5m2(sv[20], 0.f);
        Q8na[(size_t)b * HW + g0] = make_uint4(w8[0], w8[1], w8[2], w8[3]);
        Q8nb[(size_t)b * HW + g0] = make_uint2(w8[4], w8[5]);
    }
}

// ---------------------------------------------------------------------------
__global__ __launch_bounds__(256) void k_final(const float* __restrict__ part,
                                               float* __restrict__ out) {
    int tid = threadIdx.x;
    float s = part[tid] + part[tid + 256] + part[tid + 512] + part[tid + 768];
#pragma unroll
    for (int off = 32; off > 0; off >>= 1) s += __shfl_down(s, off);
    __shared__ float red[4];
    int lane = tid & 63, wv = tid >> 6;
    if (lane == 0) red[wv] = s;
    __syncthreads();
    if (tid == 0) out[0] = (red[0] + red[1] + red[2] + red[3]) / (float)NPIX;
}

// ---------------------------------------------------------------------------
extern "C" void kernel_launch(void* const* d_in, const int* in_sizes, int n_in,
                              void* d_out, int out_size, void* d_ws, size_t ws_size,
                              hipStream_t stream) {
    const float* logits = (const float*)d_in[0];
    const float* images = (const float*)d_in[1];
    const int*   labels = (const int*)d_in[2];
    float* out = (float*)d_out;

    unsigned int* ws = (unsigned int*)d_ws;
    unsigned int* Upk = ws;                                   // NB2
    unsigned int* QA  = ws +   (size_t)NB2;                   // NB2 f16 ping
    unsigned int* QB  = ws + 2*(size_t)NB2;                   // NB2 f16 pong
    unsigned int* Mpk = ws + 3*(size_t)NB2;                   // NB2
    unsigned int* ENT = ws + 4*(size_t)NB2;                   // 1024*48*256 u32 = 50.3MB
    unsigned int* CNT = ENT + (size_t)1024*CAP*256;           // 262144 u32
    unsigned int* WPD = CNT + (size_t)NPIX;                   // 262144 u32
    uint4*        Q8Aa = (uint4*)(WPD + (size_t)NPIX);        // NPIX uint4
    uint4*        Q8Ba = Q8Aa + (size_t)NPIX;                 // NPIX uint4
    uint2*        Q8Ab = (uint2*)(Q8Ba + (size_t)NPIX);       // NPIX uint2
    uint2*        Q8Bb = Q8Ab + (size_t)NPIX;                 // NPIX uint2
    float*        KT  = (float*)(Q8Bb + (size_t)NPIX);        // 64 f32
    float*        PART = KT + 64;                             // 1024 f32

    k_init<<<NPIX/256, 256, 0, stream>>>(logits, Upk, QA, Q8Aa, Q8Ab, KT);
    k_wgt<<<B*256, 256, 0, stream>>>(images, ENT, CNT, WPD);

    unsigned int* cur = QA;  unsigned int* oth = QB;
    uint4* c8a = Q8Aa;       uint4* o8a = Q8Ba;
    uint2* c8b = Q8Ab;       uint2* o8b = Q8Bb;
    for (int it = 0; it < 5; ++it) {
        k_gauss<<<B*NP*16, 256, 0, stream>>>(cur, Mpk, KT);
        k_update<<<B*256, 256, 0, stream>>>(c8a, c8b, Upk, Mpk, ENT, CNT, WPD,
                                            oth, o8a, o8b,
                                            (it == 4) ? labels : nullptr, PART);
        unsigned int* t = cur; cur = oth; oth = t;
        uint4* ta = c8a; c8a = o8a; o8a = ta;
        uint2* tb = c8b; c8b = o8b; o8b = tb;
    }

    k_final<<<1, 256, 0, stream>>>(PART, out);
    (void)in_sizes; (void)n_in; (void)out_size; (void)ws_size;
}